// Round 14
// baseline (241.274 us; speedup 1.0000x reference)
//
#include <hip/hip_runtime.h>

#define NPIX 9216
#define IMH 96
#define IMW 96
#define NC 21
#define NCH 22          // 21 classes + norm channel
#define NMON 126        // monomials of degree <=4 in 5 vars
#define RAD 15
#define NITER 5
#define MSZ 2772        // 126*22, one M buffer
#define HP 78           // halo pixels per block: 48 own + 15 each side
#define SP2 79          // s_sh pitch (79%32=15, bank-safe)
#define QP 25           // per-px channel pitch
#define NT 512          // 8 waves/block, grid 192

// spatial taps exp(-d^2/18), sigma=3
__constant__ float GW[16] = {
    1.0f, 0.945959f, 0.800737f, 0.606531f, 0.411112f, 0.249352f,
    0.135335f, 0.0657285f, 0.0285655f, 0.0111090f, 0.00386592f,
    0.00120386f, 0.000335463f, 8.36523e-05f, 1.86640e-05f, 3.72665e-06f};

// near-minimax deg-4 poly for exp(t) on [0, 1.0384] (all coeffs > 0)
__constant__ float d_bk[5] = {1.000000f, 0.998959f, 0.509936f, 0.139441f, 0.070024f};

// ---- P: conv + softmax + phi + stage1 + conv-x; block=(row,half) ----
__global__ __launch_bounds__(NT) void prep_kernel(
    const float* __restrict__ img, const float* __restrict__ net_w,
    const float* __restrict__ net_b,
    float* __restrict__ u, float* __restrict__ phi,
    float* __restrict__ M0, float* __restrict__ sx_out)
{
    __shared__ float wsh[588];
    __shared__ float sg_sh[NMON];
    __shared__ float ex_sh[NMON * 5];
    __shared__ float pt[HP * QP];
    __shared__ float env[HP];
    __shared__ float cq[HP * QP];
    __shared__ float s_sh[NCH * SP2];
    __shared__ float phi_sh[NMON * 48];   // own-px phi tile (24 KB)
    const int tid = threadIdx.x;
    const int row = blockIdx.x >> 1, h = blockIdx.x & 1;
    const int base = row * 96, x0 = h * 48 - 15;   // gpx = x0 + l

    for (int i = tid; i < 567; i += NT) wsh[i] = net_w[i];
    if (tid < 21) wsh[567 + tid] = net_b[tid];
    if (tid < NMON) {
        const int m = tid;
        int e1 = 0, e2 = 0, e3 = 0, e4 = 0, e5 = 0, cnt = 0;
        bool done = false;
        for (int a = 0; a <= 4 && !done; a++)
            for (int b2 = 0; b2 <= 4 - a && !done; b2++)
                for (int c = 0; c <= 4 - a - b2 && !done; c++)
                    for (int d = 0; d <= 4 - a - b2 - c && !done; d++) {
                        const int rem = 4 - a - b2 - c - d;
                        if (m - cnt <= rem) {
                            e1 = a; e2 = b2; e3 = c; e4 = d; e5 = m - cnt;
                            done = true;
                        } else cnt += rem + 1;
                    }
        const float fact[5] = {1.f, 1.f, 2.f, 6.f, 24.f};
        const int k = e1 + e2 + e3 + e4 + e5;
        sg_sh[m] = sqrtf(d_bk[k] * fact[k] /
                         (fact[e1] * fact[e2] * fact[e3] * fact[e4] * fact[e5]));
        ex_sh[m * 5 + 0] = (float)e1; ex_sh[m * 5 + 1] = (float)e2;
        ex_sh[m * 5 + 2] = (float)e3; ex_sh[m * 5 + 3] = (float)e4;
        ex_sh[m * 5 + 4] = (float)e5;
    }
    __syncthreads();

    // unary conv over halo px
    for (int t = tid; t < HP * NC; t += NT) {
        const int l = t % HP, o = t / HP;
        const int gpx = x0 + l;
        if (gpx < 0 || gpx >= 96) continue;
        float acc = wsh[567 + o];
        for (int ci = 0; ci < 3; ci++)
            for (int ky = 0; ky < 3; ky++)
                for (int kx = 0; kx < 3; kx++) {
                    const int ii = row + ky - 1, jj = gpx + kx - 1;
                    float v = 0.f;
                    if (ii >= 0 && ii < IMH && jj >= 0 && jj < IMW)
                        v = img[ci * NPIX + ii * IMW + jj];
                    acc = fmaf(v, wsh[o * 27 + (ci * 3 + ky) * 3 + kx], acc);
                }
        cq[l * QP + o] = acc;
        if (l >= 15 && l < 63) u[(size_t)o * NPIX + base + gpx] = acc;
    }
    // features + pow tables
    if (tid < HP) {
        const int gpx = x0 + tid;
        if (gpx >= 0 && gpx < 96) {
            const float fv[5] = {(float)gpx * (1.0f / 160.0f),
                                 (float)row * (1.0f / 160.0f),
                                 img[0 * NPIX + base + gpx] * (1.0f / 3.0f),
                                 img[1 * NPIX + base + gpx] * (1.0f / 3.0f),
                                 img[2 * NPIX + base + gpx] * (1.0f / 3.0f)};
            env[tid] = __expf(-0.5f * (fv[0]*fv[0] + fv[1]*fv[1] + fv[2]*fv[2] +
                                       fv[3]*fv[3] + fv[4]*fv[4]));
            #pragma unroll
            for (int v = 0; v < 5; v++) {
                float p = 1.f;
                #pragma unroll
                for (int e = 0; e < 5; e++) { pt[tid * QP + v * 5 + e] = p; p *= fv[v]; }
            }
        }
    }
    __syncthreads();
    // softmax (zero-fill invalid halo px -> boundary-exact conv-x)
    if (tid < HP) {
        const int gpx = x0 + tid;
        if (gpx < 0 || gpx >= 96) {
            #pragma unroll
            for (int o = 0; o < NCH; o++) s_sh[o * SP2 + tid] = 0.f;
        } else {
            float a[NC];
            #pragma unroll
            for (int o = 0; o < NC; o++) a[o] = cq[tid * QP + o];
            float mx = a[0];
            #pragma unroll
            for (int o = 1; o < NC; o++) mx = fmaxf(mx, a[o]);
            float sum = 0.f;
            #pragma unroll
            for (int o = 0; o < NC; o++) { a[o] = __expf(a[o] - mx); sum += a[o]; }
            const float inv = 1.f / sum;
            #pragma unroll
            for (int o = 0; o < NC; o++) s_sh[o * SP2 + tid] = a[o] * inv;
            s_sh[21 * SP2 + tid] = 1.f;
        }
    }
    // phi for own 48 px (LDS tile + global)
    for (int t = tid; t < NMON * 48; t += NT) {
        const int m = t / 48, k = t % 48;
        const int l = k + 15;
        float p = env[l] * sg_sh[m];
        p *= pt[l * QP + 0 + (int)ex_sh[m * 5 + 0]];
        p *= pt[l * QP + 5 + (int)ex_sh[m * 5 + 1]];
        p *= pt[l * QP + 10 + (int)ex_sh[m * 5 + 2]];
        p *= pt[l * QP + 15 + (int)ex_sh[m * 5 + 3]];
        p *= pt[l * QP + 20 + (int)ex_sh[m * 5 + 4]];
        phi_sh[t] = p;
        phi[(size_t)m * NPIX + base + h * 48 + k] = p;
    }
    __syncthreads();

    // stage1 (own 48 px, phi from LDS)
    for (int t = tid; t < MSZ; t += NT) {
        const int m = t / NCH, c = t % NCH;
        const float* pr = phi_sh + m * 48;
        const float* sr = s_sh + c * SP2 + 15;
        float acc = 0.f;
        #pragma unroll 8
        for (int k = 0; k < 48; k++) acc = fmaf(pr[k], sr[k], acc);
        atomicAdd(&M0[t], acc);
    }
    // conv-x (own 48 px)
    for (int t = tid; t < NCH * 48; t += NT) {
        const int ch = t / 48, k = t % 48, l = k + 15;
        const float* sr = s_sh + ch * SP2;
        float a = GW[0] * sr[l];
        #pragma unroll
        for (int d = 1; d <= RAD; d++)
            a = fmaf(GW[d], sr[l - d] + sr[l + d], a);
        sx_out[(size_t)ch * NPIX + base + h * 48 + k] = a;
    }
}

// ---- KBA: conv-y + stage2 + combine + softmax (+ stage1/conv-x next it) ----
__global__ __launch_bounds__(NT) void kba_kernel(
    const float* __restrict__ sx_in, float* __restrict__ sx_out,
    const float* __restrict__ phi,
    const float* __restrict__ Mcur, float* __restrict__ Mnext,
    float* __restrict__ Mzero, const float* __restrict__ u,
    const float* __restrict__ sp_w, const float* __restrict__ sp_b,
    const float* __restrict__ bl_w, const float* __restrict__ bl_b,
    const float* __restrict__ comp_w, const float* __restrict__ comp_b,
    float* __restrict__ out, int write_out, int doA)
{
    __shared__ float Msh[NMON * 24];    // pitch 24, cols 22/23 = 0
    __shared__ float cy_sh[HP * QP];    // conv-y; later aliased as q
    __shared__ float blv_sh[HP * QP];
    __shared__ float mp_sh[HP * QP];
    __shared__ float s_sh[NCH * SP2];
    __shared__ float wsh[1449];
    const int tid = threadIdx.x;
    const int row = blockIdx.x >> 1, h = blockIdx.x & 1;
    const int base = row * 96, x0 = h * 48 - 15;

    for (int t = tid; t < NMON * 24; t += NT) {
        const int m = t / 24, c = t % 24;
        Msh[t] = (c < NCH) ? Mcur[m * NCH + c] : 0.f;
    }
    for (int i = tid; i < 441; i += NT) {
        wsh[i] = sp_w[i]; wsh[441 + i] = bl_w[i]; wsh[882 + i] = comp_w[i];
    }
    if (tid < 21) {
        wsh[1323 + tid] = sp_b[tid]; wsh[1344 + tid] = bl_b[tid];
        wsh[1365 + tid] = comp_b[tid];
    }
    {   // zero M consumed last dispatch (15 per block x 192 blocks >= 2772)
        const int idx = blockIdx.x * 15 + tid;
        if (tid < 15 && idx < MSZ) Mzero[idx] = 0.f;
    }
    // conv-y over halo px
    for (int t = tid; t < NCH * HP; t += NT) {
        const int l = t % HP, ch = t / HP;
        const int gpx = x0 + l;
        if (gpx < 0 || gpx >= 96) continue;
        const float* plane = sx_in + (size_t)ch * NPIX;
        float a = GW[0] * plane[base + gpx];
        #pragma unroll
        for (int d = 1; d <= RAD; d++) {
            const float tp = (row - d >= 0) ? plane[base - d * IMW + gpx] : 0.f;
            const float bt = (row + d < IMH) ? plane[base + d * IMW + gpx] : 0.f;
            a = fmaf(GW[d], tp + bt, a);
        }
        cy_sh[l * QP + ch] = a;
    }
    __syncthreads();

    // stage2 over halo px: task = (l, 3-channel group)
    for (int t = tid; t < HP * 8; t += NT) {
        const int l = t % HP, c0 = (t / HP) * 3;
        const int gpx = x0 + l;
        if (gpx < 0 || gpx >= 96) continue;
        float a0 = 0.f, a1 = 0.f, a2 = 0.f;
        for (int m = 0; m < NMON; m++) {
            const float ph = phi[(size_t)m * NPIX + base + gpx];
            const float* Mr = Msh + m * 24 + c0;
            a0 = fmaf(ph, Mr[0], a0);
            a1 = fmaf(ph, Mr[1], a1);
            a2 = fmaf(ph, Mr[2], a2);
        }
        blv_sh[l * QP + c0] = a0;
        if (c0 + 1 < NCH) blv_sh[l * QP + c0 + 1] = a1;
        if (c0 + 2 < NCH) blv_sh[l * QP + c0 + 2] = a2;
    }
    __syncthreads();

    // mp = sp_b + bl_b + (sp_w@cy)/norm + (bl_w@blv)/norm
    for (int t = tid; t < HP * NC; t += NT) {
        const int l = t % HP, o = t / HP;
        const int gpx = x0 + l;
        if (gpx < 0 || gpx >= 96) continue;
        const float* cyr = cy_sh + l * QP;
        const float* blr = blv_sh + l * QP;
        float dS = 0.f, dB = 0.f;
        #pragma unroll
        for (int c = 0; c < NC; c++) {
            dS = fmaf(wsh[o * NC + c], cyr[c], dS);
            dB = fmaf(wsh[441 + o * NC + c], blr[c], dB);
        }
        mp_sh[l * QP + o] = wsh[1323 + o] + wsh[1344 + o] +
                            dS / cyr[21] + dB / blr[21];
    }
    __syncthreads();

    // q = u - (comp_w @ mp + comp_b)   (aliases cy_sh)
    for (int t = tid; t < HP * NC; t += NT) {
        const int l = t % HP, o = t / HP;
        const int gpx = x0 + l;
        if (gpx < 0 || gpx >= 96) continue;
        const float* mpr = mp_sh + l * QP;
        float d = wsh[1365 + o];
        #pragma unroll
        for (int c = 0; c < NC; c++) d = fmaf(wsh[882 + o * NC + c], mpr[c], d);
        cy_sh[l * QP + o] = u[(size_t)o * NPIX + base + gpx] - d;
    }
    __syncthreads();

    // softmax per halo px -> s_sh (zero-fill invalid); out for own px
    if (tid < HP) {
        const int gpx = x0 + tid;
        if (gpx < 0 || gpx >= 96) {
            #pragma unroll
            for (int o = 0; o < NCH; o++) s_sh[o * SP2 + tid] = 0.f;
        } else {
            float q[NC];
            #pragma unroll
            for (int o = 0; o < NC; o++) q[o] = cy_sh[tid * QP + o];
            float mx = q[0];
            #pragma unroll
            for (int o = 1; o < NC; o++) mx = fmaxf(mx, q[o]);
            float sum = 0.f;
            #pragma unroll
            for (int o = 0; o < NC; o++) { q[o] = __expf(q[o] - mx); sum += q[o]; }
            const float inv = 1.f / sum;
            #pragma unroll
            for (int o = 0; o < NC; o++) {
                const float sv = q[o] * inv;
                s_sh[o * SP2 + tid] = sv;
                if (write_out && tid >= 15 && tid < 63)
                    out[(size_t)o * NPIX + base + gpx] = sv;
            }
            s_sh[21 * SP2 + tid] = 1.f;
        }
    }
    __syncthreads();

    if (doA) {
        // stage1: own 48 px, phi from global (row segment is float4-aligned)
        for (int t = tid; t < MSZ; t += NT) {
            const int m = t / NCH, c = t % NCH;
            const float* pr = phi + (size_t)m * NPIX + base + h * 48;
            const float* sr = s_sh + c * SP2 + 15;
            float acc = 0.f;
            #pragma unroll
            for (int p4 = 0; p4 < 12; p4++) {
                const float4 pv = *(const float4*)(pr + p4 * 4);
                acc += pv.x * sr[p4 * 4] + pv.y * sr[p4 * 4 + 1] +
                       pv.z * sr[p4 * 4 + 2] + pv.w * sr[p4 * 4 + 3];
            }
            atomicAdd(&Mnext[t], acc);
        }
        // conv-x: own 48 px
        for (int t = tid; t < NCH * 48; t += NT) {
            const int ch = t / 48, k = t % 48, l = k + 15;
            const float* sr = s_sh + ch * SP2;
            float a = GW[0] * sr[l];
            #pragma unroll
            for (int d = 1; d <= RAD; d++)
                a = fmaf(GW[d], sr[l - d] + sr[l + d], a);
            sx_out[(size_t)ch * NPIX + base + h * 48 + k] = a;
        }
    }
}

extern "C" void kernel_launch(void* const* d_in, const int* in_sizes, int n_in,
                              void* d_out, int out_size, void* d_ws, size_t ws_size,
                              hipStream_t stream) {
    const float* img    = (const float*)d_in[0];
    const float* net_w  = (const float*)d_in[1];
    const float* net_b  = (const float*)d_in[2];
    const float* sp_w   = (const float*)d_in[3];
    const float* sp_b   = (const float*)d_in[4];
    const float* bl_w   = (const float*)d_in[5];
    const float* bl_b   = (const float*)d_in[6];
    const float* comp_w = (const float*)d_in[7];
    const float* comp_b = (const float*)d_in[8];

    float* M   = (float*)d_ws;                   // [3][2772]
    float* u   = M + 3 * MSZ;                    // [21][NPIX]
    float* sx  = u + (size_t)NC * NPIX;          // [2][22][NPIX]
    float* phi = sx + (size_t)2 * NCH * NPIX;    // [126][NPIX]

    float* out = (float*)d_out;

    hipMemsetAsync(M, 0, 3 * MSZ * sizeof(float), stream);
    prep_kernel<<<dim3(192), dim3(NT), 0, stream>>>(
        img, net_w, net_b, u, phi, M, sx);
    for (int it = 0; it < NITER; it++) {
        float* Mcur  = M + (it % 3) * MSZ;
        float* Mnext = M + ((it + 1) % 3) * MSZ;
        float* Mzero = M + ((it + 2) % 3) * MSZ;
        kba_kernel<<<dim3(192), dim3(NT), 0, stream>>>(
            sx + (size_t)(it & 1) * NCH * NPIX,
            sx + (size_t)((it + 1) & 1) * NCH * NPIX,
            phi, Mcur, Mnext, Mzero, u,
            sp_w, sp_b, bl_w, bl_b, comp_w, comp_b,
            out, it == NITER - 1 ? 1 : 0, it < NITER - 1 ? 1 : 0);
    }
}